// Round 4
// baseline (2139.790 us; speedup 1.0000x reference)
//
#include <hip/hip_runtime.h>

// Problem dims
#define Bn    128
#define Ntok  49
#define CIN   2048
#define Gq    256
#define Dm    768
#define Hh    8
#define HDd   96
#define FFd   2048
#define NCLS  12547
#define DUPn  50

typedef __attribute__((ext_vector_type(8))) short short8;
typedef __attribute__((ext_vector_type(4))) short short4v;
typedef __attribute__((ext_vector_type(4))) float floatx4;

__device__ __forceinline__ unsigned short f2bf(float f) {
  unsigned u = __builtin_bit_cast(unsigned, f);
  u += 0x7fffu + ((u >> 16) & 1u);   // round-to-nearest-even
  return (unsigned short)(u >> 16);
}
__device__ __forceinline__ float bf2f(unsigned short h) {
  return __builtin_bit_cast(float, (unsigned)h << 16);
}

// ---------------------------------------------------------------------------
// bf16-MFMA GEMM: C[M,N] = op(A[M,K] @ B[K,N] + bias).
// A: fp32 (converted in staging) or bf16 per template. B: fp32 weights.
// bias: fp32. C: bf16. fp32 accumulate.
// 128x128 tile, BK=32, 4 waves (2x2), each wave 64x64 as 4x4 of 16x16x32 MFMA.
// Requires M%128==0, N%128==0, K%32==0.
// ---------------------------------------------------------------------------
template<bool A_BF16, bool RELU>
__global__ __launch_bounds__(256)
void gemm_k(const void* __restrict__ Ap, const float* __restrict__ Bp,
            const float* __restrict__ bias, unsigned short* __restrict__ C,
            int M, int N, int K)
{
  __shared__ unsigned short As[128][40];   // [m][k], +8 pad (row 80B, 16B-aligned)
  __shared__ unsigned short Bs[128][40];   // [n][k] (B transposed)

  const int tid  = threadIdx.x;
  const int m0   = blockIdx.y << 7;
  const int n0   = blockIdx.x << 7;
  const int wave = tid >> 6, lane = tid & 63;
  const int wm   = (wave >> 1) << 6;
  const int wn   = (wave & 1) << 6;
  const int l16  = lane & 15, quad = lane >> 4;

  floatx4 acc[4][4];
  const floatx4 zero4 = {0.f, 0.f, 0.f, 0.f};
#pragma unroll
  for (int i = 0; i < 4; ++i)
#pragma unroll
    for (int j = 0; j < 4; ++j) acc[i][j] = zero4;

  for (int k0 = 0; k0 < K; k0 += 32) {
    // ---- stage A tile (128 x 32) ----
    if constexpr (A_BF16) {
      const unsigned short* A = (const unsigned short*)Ap;
      const int r = tid >> 1, c = (tid & 1) << 4;
      const unsigned short* src = A + (size_t)(m0 + r) * K + k0 + c;
      int4 v0 = *(const int4*)(src);
      int4 v1 = *(const int4*)(src + 8);
      *(int4*)&As[r][c]     = v0;
      *(int4*)&As[r][c + 8] = v1;
    } else {
      const float* A = (const float*)Ap;
      const int r = tid >> 3, c4 = (tid & 7) << 2;
#pragma unroll
      for (int p = 0; p < 4; ++p) {
        const int row = r + (p << 5);
        floatx4 v = *(const floatx4*)(A + (size_t)(m0 + row) * K + k0 + c4);
        As[row][c4 + 0] = f2bf(v.x);
        As[row][c4 + 1] = f2bf(v.y);
        As[row][c4 + 2] = f2bf(v.z);
        As[row][c4 + 3] = f2bf(v.w);
      }
    }
    // ---- stage B tile (32 x 128), fp32 -> bf16, transposed into Bs[n][k] ----
    {
      const int kr0 = tid >> 5, nc = (tid & 31) << 2;
#pragma unroll
      for (int p = 0; p < 4; ++p) {
        const int kr = kr0 + (p << 3);
        floatx4 v = *(const floatx4*)(Bp + (size_t)(k0 + kr) * N + n0 + nc);
        Bs[nc + 0][kr] = f2bf(v.x);
        Bs[nc + 1][kr] = f2bf(v.y);
        Bs[nc + 2][kr] = f2bf(v.z);
        Bs[nc + 3][kr] = f2bf(v.w);
      }
    }
    __syncthreads();

    short8 a[4], b[4];
#pragma unroll
    for (int i = 0; i < 4; ++i)
      a[i] = *(const short8*)&As[wm + (i << 4) + l16][quad << 3];
#pragma unroll
    for (int j = 0; j < 4; ++j)
      b[j] = *(const short8*)&Bs[wn + (j << 4) + l16][quad << 3];
#pragma unroll
    for (int i = 0; i < 4; ++i)
#pragma unroll
      for (int j = 0; j < 4; ++j)
        acc[i][j] = __builtin_amdgcn_mfma_f32_16x16x32_bf16(a[i], b[j], acc[i][j], 0, 0, 0);
    __syncthreads();
  }

  // ---- epilogue: C/D layout col=lane&15, row=quad*4+reg ----
#pragma unroll
  for (int j = 0; j < 4; ++j) {
    const int col = n0 + wn + (j << 4) + l16;
    const float bv = bias[col];
#pragma unroll
    for (int i = 0; i < 4; ++i) {
      const int rbase = m0 + wm + (i << 4) + (quad << 2);
#pragma unroll
      for (int r = 0; r < 4; ++r) {
        float v = acc[i][j][r] + bv;
        if constexpr (RELU) v = fmaxf(v, 0.f);
        C[(size_t)(rbase + r) * N + col] = f2bf(v);
      }
    }
  }
}

// ---------------------------------------------------------------------------
// Step-1 LayerNorm: out[row] = LN(2*query[row]) * g + b. query/g/b fp32,
// out bf16. D = 768, 256 threads (3 elems/thread).
// ---------------------------------------------------------------------------
__global__ __launch_bounds__(256)
void ln_query_k(const float* __restrict__ query, const float* __restrict__ gamma,
                const float* __restrict__ beta, unsigned short* __restrict__ out)
{
  const unsigned row = blockIdx.x;
  const float* p = query + (size_t)row * Dm;
  const int tid = threadIdx.x;

  float v[3];
#pragma unroll
  for (int i = 0; i < 3; ++i) v[i] = 2.f * p[tid + (i << 8)];

  float s1 = v[0] + v[1] + v[2];
  float s2 = v[0]*v[0] + v[1]*v[1] + v[2]*v[2];
#pragma unroll
  for (int off = 32; off; off >>= 1) {
    s1 += __shfl_down(s1, off, 64);
    s2 += __shfl_down(s2, off, 64);
  }
  __shared__ float r1[4], r2[4];
  const int wave = tid >> 6, lane = tid & 63;
  if (lane == 0) { r1[wave] = s1; r2[wave] = s2; }
  __syncthreads();
  s1 = r1[0] + r1[1] + r1[2] + r1[3];
  s2 = r2[0] + r2[1] + r2[2] + r2[3];
  const float mean = s1 * (1.f / Dm);
  const float var  = s2 * (1.f / Dm) - mean * mean;
  const float inv  = rsqrtf(var + 1e-5f);
#pragma unroll
  for (int i = 0; i < 3; ++i) {
    const int c = tid + (i << 8);
    out[(size_t)row * Dm + c] = f2bf((v[i] - mean) * inv * gamma[c] + beta[c]);
  }
}

// ---------------------------------------------------------------------------
// Residual LayerNorm: out[row] = LN(in1[row] + in2[row & mask]) * g + b.
// in1/in2/out bf16, gamma/beta fp32. D = 768.
// ---------------------------------------------------------------------------
__global__ __launch_bounds__(256)
void ln_k(const unsigned short* __restrict__ in1, const unsigned short* __restrict__ in2,
          unsigned in2mask, const float* __restrict__ gamma,
          const float* __restrict__ beta, unsigned short* __restrict__ out)
{
  const unsigned row = blockIdx.x;
  const unsigned short* p1 = in1 + (size_t)row * Dm;
  const unsigned short* p2 = in2 + (size_t)(row & in2mask) * Dm;
  const int tid = threadIdx.x;

  float v[3];
#pragma unroll
  for (int i = 0; i < 3; ++i) v[i] = bf2f(p1[tid + (i << 8)]) + bf2f(p2[tid + (i << 8)]);

  float s1 = v[0] + v[1] + v[2];
  float s2 = v[0]*v[0] + v[1]*v[1] + v[2]*v[2];
#pragma unroll
  for (int off = 32; off; off >>= 1) {
    s1 += __shfl_down(s1, off, 64);
    s2 += __shfl_down(s2, off, 64);
  }
  __shared__ float r1[4], r2[4];
  const int wave = tid >> 6, lane = tid & 63;
  if (lane == 0) { r1[wave] = s1; r2[wave] = s2; }
  __syncthreads();
  s1 = r1[0] + r1[1] + r1[2] + r1[3];
  s2 = r2[0] + r2[1] + r2[2] + r2[3];
  const float mean = s1 * (1.f / Dm);
  const float var  = s2 * (1.f / Dm) - mean * mean;
  const float inv  = rsqrtf(var + 1e-5f);
#pragma unroll
  for (int i = 0; i < 3; ++i) {
    const int c = tid + (i << 8);
    out[(size_t)row * Dm + c] = f2bf((v[i] - mean) * inv * gamma[c] + beta[c]);
  }
}

// ---------------------------------------------------------------------------
// Cross-attention, one block per (head, chunk-local batch). q batch-independent.
// 256 threads = one per query group. N=49 keys, per-thread softmax, fp32 math.
// qall/kbuf/vbuf/attno bf16.
// ---------------------------------------------------------------------------
__global__ __launch_bounds__(256)
void attn_k(const unsigned short* __restrict__ qall, const unsigned short* __restrict__ kbuf,
            const unsigned short* __restrict__ vbuf, unsigned short* __restrict__ attno,
            int b0)
{
  const int h = blockIdx.x, bl = blockIdx.y;   // bl = chunk-local batch
  const int b = b0 + bl;                       // global batch
  __shared__ float Ks[Ntok][HDd];
  __shared__ float Vs[Ntok][HDd];
  const int tid = threadIdx.x;
  const size_t base = (size_t)b * Ntok * Dm + h * HDd;
  for (int idx = tid; idx < Ntok * HDd; idx += 256) {
    const int n = idx / HDd, d = idx - n * HDd;
    Ks[n][d] = bf2f(kbuf[base + (size_t)n * Dm + d]);
    Vs[n][d] = bf2f(vbuf[base + (size_t)n * Dm + d]);
  }
  __syncthreads();

  const int g = tid;
  const unsigned short* qrow = qall + (size_t)g * Dm + h * HDd;
  float sc[Ntok];
#pragma unroll
  for (int n = 0; n < Ntok; ++n) sc[n] = 0.f;
  for (int kk = 0; kk < HDd; kk += 16) {
    float qv[16];
#pragma unroll
    for (int j = 0; j < 16; ++j) qv[j] = bf2f(qrow[kk + j]);
#pragma unroll 7
    for (int n = 0; n < Ntok; ++n) {
      float s = 0.f;
#pragma unroll
      for (int j = 0; j < 16; ++j) s += qv[j] * Ks[n][kk + j];
      sc[n] += s;
    }
  }
  const float scale = 0.10206207261596575f;  // 1/sqrt(96)
  float mx = -1e30f;
#pragma unroll
  for (int n = 0; n < Ntok; ++n) { sc[n] *= scale; mx = fmaxf(mx, sc[n]); }
  float sum = 0.f;
#pragma unroll
  for (int n = 0; n < Ntok; ++n) { sc[n] = __expf(sc[n] - mx); sum += sc[n]; }
  const float rs = 1.f / sum;

  unsigned short* orow = attno + ((size_t)bl * Gq + g) * Dm + h * HDd;
#pragma unroll 4
  for (int d = 0; d < HDd; ++d) {
    float s = 0.f;
#pragma unroll
    for (int n = 0; n < Ntok; ++n) s += sc[n] * Vs[n][d];
    orow[d] = f2bf(s * rs);
  }
}

// ---------------------------------------------------------------------------
// GroupFC for a batch chunk: out[b0+b, g*50+f] = h[b,g,:]@Wg[g] + bg.
// h bf16, Wg/bg fp32, out fp32. One block per group (251 blocks).
// Threads: 32 bgrp x 8 fgrp, each a 4b x 7f register tile.
// ---------------------------------------------------------------------------
__global__ __launch_bounds__(256)
void groupfc_k(const unsigned short* __restrict__ hb, const float* __restrict__ Wg,
               const float* __restrict__ bg, float* __restrict__ out,
               int b0, int bcnt)
{
  const int g = blockIdx.x;
  __shared__ float Hs[128][65];
  __shared__ float Ws[64][56];
  const int tid  = threadIdx.x;
  const int bgrp = tid >> 3, fgrp = tid & 7;
  const int bb0 = bgrp << 2, f0 = fgrp * 7;
  const bool active = bb0 < bcnt;

  float acc[4][7];
#pragma unroll
  for (int i = 0; i < 4; ++i)
#pragma unroll
    for (int j = 0; j < 7; ++j) acc[i][j] = 0.f;

  for (int k0 = 0; k0 < Dm; k0 += 64) {
    for (int q = tid; q < bcnt * 16; q += 256) {
      const int r = q >> 4, c = (q & 15) << 2;
      short4v v = *(const short4v*)(hb + ((size_t)r * Gq + g) * Dm + k0 + c);
      Hs[r][c + 0] = bf2f((unsigned short)v.x);
      Hs[r][c + 1] = bf2f((unsigned short)v.y);
      Hs[r][c + 2] = bf2f((unsigned short)v.z);
      Hs[r][c + 3] = bf2f((unsigned short)v.w);
    }
    for (int idx = tid; idx < 64 * 56; idx += 256) {
      const int k = idx / 56, f = idx - k * 56;
      Ws[k][f] = (f < DUPn) ? Wg[((size_t)g * Dm + k0 + k) * DUPn + f] : 0.f;
    }
    __syncthreads();
    if (active) {
#pragma unroll 4
      for (int k = 0; k < 64; ++k) {
        float hv[4], wv[7];
#pragma unroll
        for (int i = 0; i < 4; ++i) hv[i] = Hs[bb0 + i][k];
#pragma unroll
        for (int j = 0; j < 7; ++j) wv[j] = Ws[k][f0 + j];
#pragma unroll
        for (int i = 0; i < 4; ++i)
#pragma unroll
          for (int j = 0; j < 7; ++j) acc[i][j] += hv[i] * wv[j];
      }
    }
    __syncthreads();
  }
  if (active) {
#pragma unroll
    for (int i = 0; i < 4; ++i)
#pragma unroll
      for (int j = 0; j < 7; ++j) {
        const int f = f0 + j, c = g * DUPn + f;
        if (f < DUPn && c < NCLS)
          out[(size_t)(b0 + bb0 + i) * NCLS + c] = acc[i][j] + bg[c];
      }
  }
}

// ---------------------------------------------------------------------------

template<bool AB, bool RELU>
static inline void gemm_launch(const void* A, const float* Bm, const float* bias,
                               unsigned short* C, int M, int N, int K, hipStream_t s) {
  dim3 grid(N >> 7, M >> 7);
  gemm_k<AB, RELU><<<grid, 256, 0, s>>>(A, Bm, bias, C, M, N, K);
}

extern "C" void kernel_launch(void* const* d_in, const int* in_sizes, int n_in,
                              void* d_out, int out_size, void* d_ws, size_t ws_size,
                              hipStream_t stream) {
  const float* x       = (const float*)d_in[0];
  const float* W_embed = (const float*)d_in[1];
  const float* b_embed = (const float*)d_in[2];
  const float* query   = (const float*)d_in[3];
  const float* Wq = (const float*)d_in[4];  const float* bq  = (const float*)d_in[5];
  const float* Wk = (const float*)d_in[6];  const float* bk  = (const float*)d_in[7];
  const float* Wv = (const float*)d_in[8];  const float* bv  = (const float*)d_in[9];
  const float* Wo = (const float*)d_in[10]; const float* bo  = (const float*)d_in[11];
  const float* g1 = (const float*)d_in[12]; const float* be1 = (const float*)d_in[13];
  const float* g2 = (const float*)d_in[14]; const float* be2 = (const float*)d_in[15];
  const float* g3 = (const float*)d_in[16]; const float* be3 = (const float*)d_in[17];
  const float* W1 = (const float*)d_in[18]; const float* b1  = (const float*)d_in[19];
  const float* W2 = (const float*)d_in[20]; const float* b2  = (const float*)d_in[21];
  const float* Wg = (const float*)d_in[22]; const float* bg  = (const float*)d_in[23];
  float* out = (float*)d_out;              // fp32 logits (reference output dtype)

  // ---- workspace carve (bf16 elements). Fixed part ~29.4 MB. ----
  unsigned short* ws   = (unsigned short*)d_ws;
  unsigned short* tbuf = ws;               // 256*768
  unsigned short* qall = tbuf + 196608;    // 256*768
  unsigned short* mem  = qall + 196608;    // 6272*768
  unsigned short* kbuf = mem  + 4816896;
  unsigned short* vbuf = kbuf + 4816896;
  unsigned short* attc = vbuf + 4816896;   // chunk: CB*256*768 (reused as ff2)

  // Pick batch-chunk size CB from ws_size (deterministic per call).
  // Chunk needs CB*256*(768*3 + 2048) bf16 elements.
  int CB = 128;
  for (;;) {
    size_t need = (size_t)2 * 196608 + (size_t)3 * 4816896 + (size_t)CB * 256 * 4352;
    if (need * 2 <= ws_size || CB == 4) break;
    CB >>= 1;
  }
  const size_t cstride = (size_t)CB * 196608;          // CB*256*768
  unsigned short* oprc = attc + cstride;               // chunk oproj (reused as h)
  unsigned short* t2c  = oprc + cstride;               // chunk t2
  unsigned short* ff1c = t2c + cstride;                // chunk CB*256*2048
  unsigned short* ff2c = attc;
  unsigned short* hc   = oprc;

  // 1. t = LN(query + query)            [batch-independent]
  ln_query_k<<<Gq, 256, 0, stream>>>(query, g1, be1, tbuf);
  // 2. qall = t @ Wq + bq               [batch-independent]
  gemm_launch<true, false>(tbuf, Wq, bq, qall, Gq, Dm, Dm, stream);
  // 3. mem = relu(x @ W_embed + b_embed)
  gemm_launch<false, true>(x, W_embed, b_embed, mem, Bn * Ntok, Dm, CIN, stream);
  // 4/5. K, V projections
  gemm_launch<true, false>(mem, Wk, bk, kbuf, Bn * Ntok, Dm, Dm, stream);
  gemm_launch<true, false>(mem, Wv, bv, vbuf, Bn * Ntok, Dm, Dm, stream);

  // ---- decoder tail, chunked over batch ----
  for (int b0 = 0; b0 < Bn; b0 += CB) {
    const int rows = CB * Gq;
    // 6. cross-attention -> attc (chunk-local)
    attn_k<<<dim3(Hh, CB), 256, 0, stream>>>(qall, kbuf, vbuf, attc, b0);
    // 7. oproj = attc @ Wo + bo
    gemm_launch<true, false>(attc, Wo, bo, oprc, rows, Dm, Dm, stream);
    // 8. t2 = LN(t + oproj)   (t broadcast: local row & 255)
    ln_k<<<rows, 256, 0, stream>>>(oprc, tbuf, 255u, g2, be2, t2c);
    // 9. FFN
    gemm_launch<true, true>(t2c, W1, b1, ff1c, rows, FFd, Dm, stream);
    gemm_launch<true, false>(ff1c, W2, b2, ff2c, rows, Dm, FFd, stream);
    // 10. h = LN(t2 + ff2)
    ln_k<<<rows, 256, 0, stream>>>(ff2c, t2c, 0xFFFFFFFFu, g3, be3, hc);
    // 11. GroupFC -> logits for this chunk
    groupfc_k<<<251, 256, 0, stream>>>(hc, Wg, bg, out, b0, CB);
  }
}

// Round 5
// 1223.782 us; speedup vs baseline: 1.7485x; 1.7485x over previous
//
#include <hip/hip_runtime.h>

// Problem dims
#define Bn    128
#define Ntok  49
#define CIN   2048
#define Gq    256
#define Dm    768
#define Hh    8
#define HDd   96
#define FFd   2048
#define NCLS  12547
#define DUPn  50

typedef __attribute__((ext_vector_type(8))) short short8;
typedef __attribute__((ext_vector_type(4))) short short4v;
typedef __attribute__((ext_vector_type(4))) float floatx4;

__device__ __forceinline__ unsigned short f2bf(float f) {
  unsigned u = __builtin_bit_cast(unsigned, f);
  u += 0x7fffu + ((u >> 16) & 1u);   // round-to-nearest-even
  return (unsigned short)(u >> 16);
}
__device__ __forceinline__ float bf2f(unsigned short h) {
  return __builtin_bit_cast(float, (unsigned)h << 16);
}

// async global->LDS, 16 B per lane; LDS dest = wave-uniform base + lane*16
__device__ __forceinline__ void gl_lds16(const unsigned short* g, unsigned short* l) {
  __builtin_amdgcn_global_load_lds(
      (__attribute__((address_space(1))) void*)g,
      (__attribute__((address_space(3))) void*)l, 16, 0, 0);
}

// ---------------------------------------------------------------------------
// m97-style bf16 GEMM-BT: C[M,N] = op(A[M,K] @ Bt[N,K]^T + bias)
// A,Bt,C bf16; bias fp32; fp32 accumulate. 128x128 tile, BK=32, 4 waves,
// each wave 64x64 as 4x4 of 16x16x32 MFMA. global_load_lds staging,
// unpadded LDS. Requires M%128==0, N%128==0, K%32==0.
// ---------------------------------------------------------------------------
__global__ __launch_bounds__(256)
void gemm_bt(const unsigned short* __restrict__ A,
             const unsigned short* __restrict__ Bt,
             const float* __restrict__ bias,
             unsigned short* __restrict__ C,
             int M, int N, int K, int relu)
{
  __shared__ unsigned short As[128 * 32];   // 8 KB, linear [m][k]
  __shared__ unsigned short Bs[128 * 32];   // 8 KB, linear [n][k]

  const int tid  = threadIdx.x;
  const int m0   = blockIdx.y << 7;
  const int n0   = blockIdx.x << 7;
  const int wave = tid >> 6, lane = tid & 63;
  const int wm   = (wave >> 1) << 6;
  const int wn   = (wave & 1) << 6;
  const int l16  = lane & 15, quad = lane >> 4;

  // staging: wave w covers rows [w*32, w*32+32), two 1KB waves-worth each
  const int srow = (wave << 5) + (lane >> 2);
  const int scol = (lane & 3) << 3;
  const unsigned short* gA = A  + (size_t)(m0 + srow) * K + scol;
  const unsigned short* gB = Bt + (size_t)(n0 + srow) * K + scol;
  const size_t rstep = (size_t)16 * K;
  unsigned short* lA = &As[wave << 10];
  unsigned short* lB = &Bs[wave << 10];

  floatx4 acc[4][4];
  const floatx4 zero4 = {0.f, 0.f, 0.f, 0.f};
#pragma unroll
  for (int i = 0; i < 4; ++i)
#pragma unroll
    for (int j = 0; j < 4; ++j) acc[i][j] = zero4;

  for (int k0 = 0; k0 < K; k0 += 32) {
    gl_lds16(gA + k0,         lA);
    gl_lds16(gA + k0 + rstep, lA + 512);
    gl_lds16(gB + k0,         lB);
    gl_lds16(gB + k0 + rstep, lB + 512);
    __syncthreads();   // drains vmcnt(0) before barrier

    short8 a[4], b[4];
#pragma unroll
    for (int i = 0; i < 4; ++i)
      a[i] = *(const short8*)&As[(wm + (i << 4) + l16) * 32 + (quad << 3)];
#pragma unroll
    for (int j = 0; j < 4; ++j)
      b[j] = *(const short8*)&Bs[(wn + (j << 4) + l16) * 32 + (quad << 3)];
#pragma unroll
    for (int i = 0; i < 4; ++i)
#pragma unroll
      for (int j = 0; j < 4; ++j)
        acc[i][j] = __builtin_amdgcn_mfma_f32_16x16x32_bf16(a[i], b[j], acc[i][j], 0, 0, 0);
    __syncthreads();
  }

  // epilogue: C/D layout col=lane&15, row=quad*4+reg
#pragma unroll
  for (int j = 0; j < 4; ++j) {
    const int col = n0 + wn + (j << 4) + l16;
    const float bv = bias[col];
#pragma unroll
    for (int i = 0; i < 4; ++i) {
      const int rbase = m0 + wm + (i << 4) + (quad << 2);
#pragma unroll
      for (int r = 0; r < 4; ++r) {
        float v = acc[i][j][r] + bv;
        if (relu) v = fmaxf(v, 0.f);
        C[(size_t)(rbase + r) * N + col] = f2bf(v);
      }
    }
  }
}

// ---------------------------------------------------------------------------
// fp32 -> bf16 elementwise (n multiple of 4)
// ---------------------------------------------------------------------------
__global__ __launch_bounds__(256)
void cvt_k(const float* __restrict__ in, unsigned short* __restrict__ out, int n4)
{
  const int i = blockIdx.x * 256 + threadIdx.x;
  if (i < n4) {
    floatx4 v = ((const floatx4*)in)[i];
    short4v s;
    s.x = (short)f2bf(v.x); s.y = (short)f2bf(v.y);
    s.z = (short)f2bf(v.z); s.w = (short)f2bf(v.w);
    ((short4v*)out)[i] = s;
  }
}

// ---------------------------------------------------------------------------
// transpose + convert: in fp32 [K][N] -> out bf16 [N][K]. K,N % 32 == 0.
// ---------------------------------------------------------------------------
__global__ __launch_bounds__(256)
void transcvt_k(const float* __restrict__ in, unsigned short* __restrict__ out,
                int K, int N)
{
  __shared__ float tile[32][33];
  const int nb = blockIdx.x << 5, kb = blockIdx.y << 5;
  const int tx = threadIdx.x & 31, ty = threadIdx.x >> 5;   // 32 x 8
#pragma unroll
  for (int i = 0; i < 4; ++i)
    tile[ty + (i << 3)][tx] = in[(size_t)(kb + ty + (i << 3)) * N + nb + tx];
  __syncthreads();
#pragma unroll
  for (int i = 0; i < 4; ++i)
    out[(size_t)(nb + ty + (i << 3)) * K + kb + tx] = f2bf(tile[tx][ty + (i << 3)]);
}

// ---------------------------------------------------------------------------
// Step-1 LayerNorm: out[row] = LN(2*query[row]) * g + b. fp32 in, bf16 out.
// ---------------------------------------------------------------------------
__global__ __launch_bounds__(256)
void ln_query_k(const float* __restrict__ query, const float* __restrict__ gamma,
                const float* __restrict__ beta, unsigned short* __restrict__ out)
{
  const unsigned row = blockIdx.x;
  const float* p = query + (size_t)row * Dm;
  const int tid = threadIdx.x;

  float v[3];
#pragma unroll
  for (int i = 0; i < 3; ++i) v[i] = 2.f * p[tid + (i << 8)];

  float s1 = v[0] + v[1] + v[2];
  float s2 = v[0]*v[0] + v[1]*v[1] + v[2]*v[2];
#pragma unroll
  for (int off = 32; off; off >>= 1) {
    s1 += __shfl_down(s1, off, 64);
    s2 += __shfl_down(s2, off, 64);
  }
  __shared__ float r1[4], r2[4];
  const int wave = tid >> 6, lane = tid & 63;
  if (lane == 0) { r1[wave] = s1; r2[wave] = s2; }
  __syncthreads();
  s1 = r1[0] + r1[1] + r1[2] + r1[3];
  s2 = r2[0] + r2[1] + r2[2] + r2[3];
  const float mean = s1 * (1.f / Dm);
  const float var  = s2 * (1.f / Dm) - mean * mean;
  const float inv  = rsqrtf(var + 1e-5f);
#pragma unroll
  for (int i = 0; i < 3; ++i) {
    const int c = tid + (i << 8);
    out[(size_t)row * Dm + c] = f2bf((v[i] - mean) * inv * gamma[c] + beta[c]);
  }
}

// ---------------------------------------------------------------------------
// Residual LayerNorm: out[row] = LN(in1[row] + in2[row & mask]) * g + b.
// in1/in2/out bf16, gamma/beta fp32.
// ---------------------------------------------------------------------------
__global__ __launch_bounds__(256)
void ln_k(const unsigned short* __restrict__ in1, const unsigned short* __restrict__ in2,
          unsigned in2mask, const float* __restrict__ gamma,
          const float* __restrict__ beta, unsigned short* __restrict__ out)
{
  const unsigned row = blockIdx.x;
  const unsigned short* p1 = in1 + (size_t)row * Dm;
  const unsigned short* p2 = in2 + (size_t)(row & in2mask) * Dm;
  const int tid = threadIdx.x;

  float v[3];
#pragma unroll
  for (int i = 0; i < 3; ++i) v[i] = bf2f(p1[tid + (i << 8)]) + bf2f(p2[tid + (i << 8)]);

  float s1 = v[0] + v[1] + v[2];
  float s2 = v[0]*v[0] + v[1]*v[1] + v[2]*v[2];
#pragma unroll
  for (int off = 32; off; off >>= 1) {
    s1 += __shfl_down(s1, off, 64);
    s2 += __shfl_down(s2, off, 64);
  }
  __shared__ float r1[4], r2[4];
  const int wave = tid >> 6, lane = tid & 63;
  if (lane == 0) { r1[wave] = s1; r2[wave] = s2; }
  __syncthreads();
  s1 = r1[0] + r1[1] + r1[2] + r1[3];
  s2 = r2[0] + r2[1] + r2[2] + r2[3];
  const float mean = s1 * (1.f / Dm);
  const float var  = s2 * (1.f / Dm) - mean * mean;
  const float inv  = rsqrtf(var + 1e-5f);
#pragma unroll
  for (int i = 0; i < 3; ++i) {
    const int c = tid + (i << 8);
    out[(size_t)row * Dm + c] = f2bf((v[i] - mean) * inv * gamma[c] + beta[c]);
  }
}

// ---------------------------------------------------------------------------
// Cross-attention, one block per (head, chunk-local batch). q batch-independent.
// 256 threads = one per query group. N=49 keys, per-thread softmax, fp32 math.
// ---------------------------------------------------------------------------
__global__ __launch_bounds__(256)
void attn_k(const unsigned short* __restrict__ qall, const unsigned short* __restrict__ kbuf,
            const unsigned short* __restrict__ vbuf, unsigned short* __restrict__ attno,
            int b0)
{
  const int h = blockIdx.x, bl = blockIdx.y;
  const int b = b0 + bl;
  __shared__ float Ks[Ntok][HDd];
  __shared__ float Vs[Ntok][HDd];
  const int tid = threadIdx.x;
  const size_t base = (size_t)b * Ntok * Dm + h * HDd;
  for (int idx = tid; idx < Ntok * HDd; idx += 256) {
    const int n = idx / HDd, d = idx - n * HDd;
    Ks[n][d] = bf2f(kbuf[base + (size_t)n * Dm + d]);
    Vs[n][d] = bf2f(vbuf[base + (size_t)n * Dm + d]);
  }
  __syncthreads();

  const int g = tid;
  const unsigned short* qrow = qall + (size_t)g * Dm + h * HDd;
  float sc[Ntok];
#pragma unroll
  for (int n = 0; n < Ntok; ++n) sc[n] = 0.f;
  for (int kk = 0; kk < HDd; kk += 16) {
    float qv[16];
#pragma unroll
    for (int j = 0; j < 16; ++j) qv[j] = bf2f(qrow[kk + j]);
#pragma unroll 7
    for (int n = 0; n < Ntok; ++n) {
      float s = 0.f;
#pragma unroll
      for (int j = 0; j < 16; ++j) s += qv[j] * Ks[n][kk + j];
      sc[n] += s;
    }
  }
  const float scale = 0.10206207261596575f;  // 1/sqrt(96)
  float mx = -1e30f;
#pragma unroll
  for (int n = 0; n < Ntok; ++n) { sc[n] *= scale; mx = fmaxf(mx, sc[n]); }
  float sum = 0.f;
#pragma unroll
  for (int n = 0; n < Ntok; ++n) { sc[n] = __expf(sc[n] - mx); sum += sc[n]; }
  const float rs = 1.f / sum;

  unsigned short* orow = attno + ((size_t)bl * Gq + g) * Dm + h * HDd;
#pragma unroll 4
  for (int d = 0; d < HDd; ++d) {
    float s = 0.f;
#pragma unroll
    for (int n = 0; n < Ntok; ++n) s += sc[n] * Vs[n][d];
    orow[d] = f2bf(s * rs);
  }
}

// ---------------------------------------------------------------------------
// GroupFC for a batch chunk: out[b0+b, g*50+f] = h[b,g,:]@Wg[g] + bg.
// h bf16, Wg/bg fp32, out fp32. One block per group (251 blocks).
// ---------------------------------------------------------------------------
__global__ __launch_bounds__(256)
void groupfc_k(const unsigned short* __restrict__ hb, const float* __restrict__ Wg,
               const float* __restrict__ bg, float* __restrict__ out,
               int b0, int bcnt)
{
  const int g = blockIdx.x;
  __shared__ float Hs[128][65];
  __shared__ float Ws[64][56];
  const int tid  = threadIdx.x;
  const int bgrp = tid >> 3, fgrp = tid & 7;
  const int bb0 = bgrp << 2, f0 = fgrp * 7;
  const bool active = bb0 < bcnt;

  float acc[4][7];
#pragma unroll
  for (int i = 0; i < 4; ++i)
#pragma unroll
    for (int j = 0; j < 7; ++j) acc[i][j] = 0.f;

  for (int k0 = 0; k0 < Dm; k0 += 64) {
    for (int q = tid; q < bcnt * 16; q += 256) {
      const int r = q >> 4, c = (q & 15) << 2;
      short4v v = *(const short4v*)(hb + ((size_t)r * Gq + g) * Dm + k0 + c);
      Hs[r][c + 0] = bf2f((unsigned short)v.x);
      Hs[r][c + 1] = bf2f((unsigned short)v.y);
      Hs[r][c + 2] = bf2f((unsigned short)v.z);
      Hs[r][c + 3] = bf2f((unsigned short)v.w);
    }
    for (int idx = tid; idx < 64 * 56; idx += 256) {
      const int k = idx / 56, f = idx - k * 56;
      Ws[k][f] = (f < DUPn) ? Wg[((size_t)g * Dm + k0 + k) * DUPn + f] : 0.f;
    }
    __syncthreads();
    if (active) {
#pragma unroll 4
      for (int k = 0; k < 64; ++k) {
        float hv[4], wv[7];
#pragma unroll
        for (int i = 0; i < 4; ++i) hv[i] = Hs[bb0 + i][k];
#pragma unroll
        for (int j = 0; j < 7; ++j) wv[j] = Ws[k][f0 + j];
#pragma unroll
        for (int i = 0; i < 4; ++i)
#pragma unroll
          for (int j = 0; j < 7; ++j) acc[i][j] += hv[i] * wv[j];
      }
    }
    __syncthreads();
  }
  if (active) {
#pragma unroll
    for (int i = 0; i < 4; ++i)
#pragma unroll
      for (int j = 0; j < 7; ++j) {
        const int f = f0 + j, c = g * DUPn + f;
        if (f < DUPn && c < NCLS)
          out[(size_t)(b0 + bb0 + i) * NCLS + c] = acc[i][j] + bg[c];
      }
  }
}

// ---------------------------------------------------------------------------

static inline void gemm_launch(const unsigned short* A, const unsigned short* Bt,
                               const float* bias, unsigned short* C,
                               int M, int N, int K, int relu, hipStream_t s) {
  dim3 grid(N >> 7, M >> 7);
  gemm_bt<<<grid, 256, 0, s>>>(A, Bt, bias, C, M, N, K, relu);
}

extern "C" void kernel_launch(void* const* d_in, const int* in_sizes, int n_in,
                              void* d_out, int out_size, void* d_ws, size_t ws_size,
                              hipStream_t stream) {
  const float* x       = (const float*)d_in[0];
  const float* W_embed = (const float*)d_in[1];
  const float* b_embed = (const float*)d_in[2];
  const float* query   = (const float*)d_in[3];
  const float* Wq = (const float*)d_in[4];  const float* bq  = (const float*)d_in[5];
  const float* Wk = (const float*)d_in[6];  const float* bk  = (const float*)d_in[7];
  const float* Wv = (const float*)d_in[8];  const float* bv  = (const float*)d_in[9];
  const float* Wo = (const float*)d_in[10]; const float* bo  = (const float*)d_in[11];
  const float* g1 = (const float*)d_in[12]; const float* be1 = (const float*)d_in[13];
  const float* g2 = (const float*)d_in[14]; const float* be2 = (const float*)d_in[15];
  const float* g3 = (const float*)d_in[16]; const float* be3 = (const float*)d_in[17];
  const float* W1 = (const float*)d_in[18]; const float* b1  = (const float*)d_in[19];
  const float* W2 = (const float*)d_in[20]; const float* b2  = (const float*)d_in[21];
  const float* Wg = (const float*)d_in[22]; const float* bg  = (const float*)d_in[23];
  float* out = (float*)d_out;              // fp32 logits

  // ---- workspace carve (bf16 elements). Fixed part ~69.5 MB. ----
  unsigned short* ws    = (unsigned short*)d_ws;
  unsigned short* tbuf  = ws;                    // 256*768
  unsigned short* qall  = tbuf  + 196608;        // 256*768
  unsigned short* mem   = qall  + 196608;        // 6272*768
  unsigned short* kbuf  = mem   + 4816896;
  unsigned short* vbuf  = kbuf  + 4816896;
  unsigned short* xbf   = vbuf  + 4816896;       // 6272*2048
  unsigned short* wembT = xbf   + 12845056;      // 768*2048
  unsigned short* wqT   = wembT + 1572864;       // 768*768
  unsigned short* wkT   = wqT   + 589824;
  unsigned short* wvT   = wkT   + 589824;
  unsigned short* woT   = wvT   + 589824;
  unsigned short* w1T   = woT   + 589824;        // 2048*768
  unsigned short* w2T   = w1T   + 1572864;       // 768*2048
  unsigned short* attc  = w2T   + 1572864;       // chunk start

  const size_t fixed_elems = 34766848;           // sum above
  int CB = 128;
  while (CB > 4 && (fixed_elems + (size_t)CB * 1114112) * 2 > ws_size) CB >>= 1;
  const size_t cstride = (size_t)CB * 196608;    // CB*256*768
  unsigned short* oprc = attc + cstride;         // chunk oproj (reused as h)
  unsigned short* t2c  = oprc + cstride;         // chunk t2
  unsigned short* ff1c = t2c  + cstride;         // chunk CB*256*2048
  unsigned short* ff2c = attc;
  unsigned short* hc   = oprc;

  // 0. one-time conversions: x -> bf16; weights -> bf16 transposed [N][K]
  cvt_k<<<(Bn * Ntok * CIN / 4 + 255) / 256, 256, 0, stream>>>(x, xbf, Bn * Ntok * CIN / 4);
  transcvt_k<<<dim3(Dm / 32, CIN / 32), 256, 0, stream>>>(W_embed, wembT, CIN, Dm);
  transcvt_k<<<dim3(Dm / 32, Dm / 32),  256, 0, stream>>>(Wq, wqT, Dm, Dm);
  transcvt_k<<<dim3(Dm / 32, Dm / 32),  256, 0, stream>>>(Wk, wkT, Dm, Dm);
  transcvt_k<<<dim3(Dm / 32, Dm / 32),  256, 0, stream>>>(Wv, wvT, Dm, Dm);
  transcvt_k<<<dim3(Dm / 32, Dm / 32),  256, 0, stream>>>(Wo, woT, Dm, Dm);
  transcvt_k<<<dim3(FFd / 32, Dm / 32), 256, 0, stream>>>(W1, w1T, Dm, FFd);
  transcvt_k<<<dim3(Dm / 32, FFd / 32), 256, 0, stream>>>(W2, w2T, FFd, Dm);

  // 1. t = LN(2*query)                  [batch-independent]
  ln_query_k<<<Gq, 256, 0, stream>>>(query, g1, be1, tbuf);
  // 2. qall = t @ Wq + bq               [batch-independent]
  gemm_launch(tbuf, wqT, bq, qall, Gq, Dm, Dm, 0, stream);
  // 3. mem = relu(x @ W_embed + b_embed)
  gemm_launch(xbf, wembT, b_embed, mem, Bn * Ntok, Dm, CIN, 1, stream);
  // 4/5. K, V projections
  gemm_launch(mem, wkT, bk, kbuf, Bn * Ntok, Dm, Dm, 0, stream);
  gemm_launch(mem, wvT, bv, vbuf, Bn * Ntok, Dm, Dm, 0, stream);

  // ---- decoder tail, chunked over batch ----
  for (int b0 = 0; b0 < Bn; b0 += CB) {
    const int rows = CB * Gq;
    attn_k<<<dim3(Hh, CB), 256, 0, stream>>>(qall, kbuf, vbuf, attc, b0);
    gemm_launch(attc, woT, bo, oprc, rows, Dm, Dm, 0, stream);
    ln_k<<<rows, 256, 0, stream>>>(oprc, tbuf, 255u, g2, be2, t2c);
    gemm_launch(t2c, w1T, b1, ff1c, rows, FFd, Dm, 1, stream);
    gemm_launch(ff1c, w2T, b2, ff2c, rows, Dm, FFd, 0, stream);
    ln_k<<<rows, 256, 0, stream>>>(ff2c, t2c, 0xFFFFFFFFu, g3, be3, hc);
    groupfc_k<<<251, 256, 0, stream>>>(hc, Wg, bg, out, b0, CB);
  }
}

// Round 6
// 987.809 us; speedup vs baseline: 2.1662x; 1.2389x over previous
//
#include <hip/hip_runtime.h>

// Problem dims
#define Bn    128
#define Ntok  49
#define CIN   2048
#define Gq    256
#define Dm    768
#define Hh    8
#define HDd   96
#define FFd   2048
#define NCLS  12547
#define DUPn  50

typedef __attribute__((ext_vector_type(8))) short short8;
typedef __attribute__((ext_vector_type(4))) short short4v;
typedef __attribute__((ext_vector_type(4))) float floatx4;

__device__ __forceinline__ unsigned short f2bf(float f) {
  unsigned u = __builtin_bit_cast(unsigned, f);
  u += 0x7fffu + ((u >> 16) & 1u);   // round-to-nearest-even
  return (unsigned short)(u >> 16);
}
__device__ __forceinline__ float bf2f(unsigned short h) {
  return __builtin_bit_cast(float, (unsigned)h << 16);
}

// async global->LDS, 16 B per lane; LDS dest = wave-uniform base + lane*16
__device__ __forceinline__ void gl_lds16(const unsigned short* g, unsigned short* l) {
  __builtin_amdgcn_global_load_lds(
      (__attribute__((address_space(1))) void*)g,
      (__attribute__((address_space(3))) void*)l, 16, 0, 0);
}

// ---------------------------------------------------------------------------
// m97-style bf16 GEMM-BT: C[M,N] = op(A[M,K] @ Bt[N,K]^T + bias)
// A,Bt,C bf16; bias fp32; fp32 accumulate. 128x128 tile, BK=32, 4 waves,
// each wave 64x64 as 4x4 of 16x16x32 MFMA. global_load_lds staging.
// ---------------------------------------------------------------------------
__global__ __launch_bounds__(256)
void gemm_bt(const unsigned short* __restrict__ A,
             const unsigned short* __restrict__ Bt,
             const float* __restrict__ bias,
             unsigned short* __restrict__ C,
             int M, int N, int K, int relu)
{
  __shared__ unsigned short As[128 * 32];
  __shared__ unsigned short Bs[128 * 32];

  const int tid  = threadIdx.x;
  const int m0   = blockIdx.y << 7;
  const int n0   = blockIdx.x << 7;
  const int wave = tid >> 6, lane = tid & 63;
  const int wm   = (wave >> 1) << 6;
  const int wn   = (wave & 1) << 6;
  const int l16  = lane & 15, quad = lane >> 4;

  const int srow = (wave << 5) + (lane >> 2);
  const int scol = (lane & 3) << 3;
  const unsigned short* gA = A  + (size_t)(m0 + srow) * K + scol;
  const unsigned short* gB = Bt + (size_t)(n0 + srow) * K + scol;
  const size_t rstep = (size_t)16 * K;
  unsigned short* lA = &As[wave << 10];
  unsigned short* lB = &Bs[wave << 10];

  floatx4 acc[4][4];
  const floatx4 zero4 = {0.f, 0.f, 0.f, 0.f};
#pragma unroll
  for (int i = 0; i < 4; ++i)
#pragma unroll
    for (int j = 0; j < 4; ++j) acc[i][j] = zero4;

  for (int k0 = 0; k0 < K; k0 += 32) {
    gl_lds16(gA + k0,         lA);
    gl_lds16(gA + k0 + rstep, lA + 512);
    gl_lds16(gB + k0,         lB);
    gl_lds16(gB + k0 + rstep, lB + 512);
    __syncthreads();

    short8 a[4], b[4];
#pragma unroll
    for (int i = 0; i < 4; ++i)
      a[i] = *(const short8*)&As[(wm + (i << 4) + l16) * 32 + (quad << 3)];
#pragma unroll
    for (int j = 0; j < 4; ++j)
      b[j] = *(const short8*)&Bs[(wn + (j << 4) + l16) * 32 + (quad << 3)];
#pragma unroll
    for (int i = 0; i < 4; ++i)
#pragma unroll
      for (int j = 0; j < 4; ++j)
        acc[i][j] = __builtin_amdgcn_mfma_f32_16x16x32_bf16(a[i], b[j], acc[i][j], 0, 0, 0);
    __syncthreads();
  }

#pragma unroll
  for (int j = 0; j < 4; ++j) {
    const int col = n0 + wn + (j << 4) + l16;
    const float bv = bias[col];
#pragma unroll
    for (int i = 0; i < 4; ++i) {
      const int rbase = m0 + wm + (i << 4) + (quad << 2);
#pragma unroll
      for (int r = 0; r < 4; ++r) {
        float v = acc[i][j][r] + bv;
        if (relu) v = fmaxf(v, 0.f);
        C[(size_t)(rbase + r) * N + col] = f2bf(v);
      }
    }
  }
}

// ---------------------------------------------------------------------------
// fp32 -> bf16 elementwise (n multiple of 4)
// ---------------------------------------------------------------------------
__global__ __launch_bounds__(256)
void cvt_k(const float* __restrict__ in, unsigned short* __restrict__ out, int n4)
{
  const int i = blockIdx.x * 256 + threadIdx.x;
  if (i < n4) {
    floatx4 v = ((const floatx4*)in)[i];
    short4v s;
    s.x = (short)f2bf(v.x); s.y = (short)f2bf(v.y);
    s.z = (short)f2bf(v.z); s.w = (short)f2bf(v.w);
    ((short4v*)out)[i] = s;
  }
}

// ---------------------------------------------------------------------------
// transpose + convert: in fp32 [K][N] -> out bf16 [N][K]. K,N % 32 == 0.
// ---------------------------------------------------------------------------
__global__ __launch_bounds__(256)
void transcvt_k(const float* __restrict__ in, unsigned short* __restrict__ out,
                int K, int N)
{
  __shared__ float tile[32][33];
  const int nb = blockIdx.x << 5, kb = blockIdx.y << 5;
  const int tx = threadIdx.x & 31, ty = threadIdx.x >> 5;   // 32 x 8
#pragma unroll
  for (int i = 0; i < 4; ++i)
    tile[ty + (i << 3)][tx] = in[(size_t)(kb + ty + (i << 3)) * N + nb + tx];
  __syncthreads();
#pragma unroll
  for (int i = 0; i < 4; ++i)
    out[(size_t)(nb + ty + (i << 3)) * K + kb + tx] = f2bf(tile[tx][ty + (i << 3)]);
}

// ---------------------------------------------------------------------------
// Wg transpose: fp32 [g][768][50] -> bf16 [g][64][768], f>=50 zero-padded.
// grid (2, 24, 251), block 256 (32x8).
// ---------------------------------------------------------------------------
__global__ __launch_bounds__(256)
void wg_trans_k(const float* __restrict__ Wg, unsigned short* __restrict__ out)
{
  __shared__ float tile[32][33];
  const int g  = blockIdx.z;
  const int nb = blockIdx.x << 5, kb = blockIdx.y << 5;
  const int tx = threadIdx.x & 31, ty = threadIdx.x >> 5;
  const float* in = Wg + (size_t)g * Dm * DUPn;
#pragma unroll
  for (int i = 0; i < 4; ++i) {
    const int f = nb + tx;
    tile[ty + (i << 3)][tx] =
        (f < DUPn) ? in[(size_t)(kb + ty + (i << 3)) * DUPn + f] : 0.f;
  }
  __syncthreads();
  unsigned short* o = out + (size_t)g * 64 * Dm;
#pragma unroll
  for (int i = 0; i < 4; ++i)
    o[(size_t)(nb + ty + (i << 3)) * Dm + kb + tx] = f2bf(tile[tx][ty + (i << 3)]);
}

// ---------------------------------------------------------------------------
// GroupFC via MFMA. One block per group g (251). M=128 batch, N=64 (f pad),
// K=768. 4 waves: wave m = (wave&1)*64, n = (wave>>1)*32; each wave 4x2 frags.
// h bf16 [b][256][768]; wgT bf16 [g][64][768]; bg fp32; out fp32.
// ---------------------------------------------------------------------------
__global__ __launch_bounds__(256)
void groupfc_k(const unsigned short* __restrict__ hb, const unsigned short* __restrict__ wgT,
               const float* __restrict__ bg, float* __restrict__ out,
               int b0, int bcnt)
{
  __shared__ unsigned short As[128 * 32];   // batch x k
  __shared__ unsigned short Bs[64 * 32];    // f x k

  const int g    = blockIdx.x;
  const int tid  = threadIdx.x;
  const int wave = tid >> 6, lane = tid & 63;
  const int wm   = (wave & 1) << 6;
  const int wn   = (wave >> 1) << 5;
  const int l16  = lane & 15, quad = lane >> 4;

  const int srow = (wave << 5) + (lane >> 2);   // A batch row (2 issues: +0,+16)
  const int brow = (wave << 4) + (lane >> 2);   // B f row (1 issue)
  const int scol = (lane & 3) << 3;
  const unsigned short* gA = hb + ((size_t)srow * Gq + g) * Dm + scol;
  const unsigned short* gB = wgT + (size_t)g * 64 * Dm + (size_t)brow * Dm + scol;
  const size_t rstepA = (size_t)16 * Gq * Dm;
  unsigned short* lA = &As[wave << 10];
  unsigned short* lB = &Bs[wave << 9];

  floatx4 acc[4][2];
  const floatx4 zero4 = {0.f, 0.f, 0.f, 0.f};
#pragma unroll
  for (int i = 0; i < 4; ++i)
#pragma unroll
    for (int j = 0; j < 2; ++j) acc[i][j] = zero4;

  for (int k0 = 0; k0 < Dm; k0 += 32) {
    gl_lds16(gA + k0,          lA);
    gl_lds16(gA + k0 + rstepA, lA + 512);
    gl_lds16(gB + k0,          lB);
    __syncthreads();

    short8 a[4], b[2];
#pragma unroll
    for (int i = 0; i < 4; ++i)
      a[i] = *(const short8*)&As[(wm + (i << 4) + l16) * 32 + (quad << 3)];
#pragma unroll
    for (int j = 0; j < 2; ++j)
      b[j] = *(const short8*)&Bs[(wn + (j << 4) + l16) * 32 + (quad << 3)];
#pragma unroll
    for (int i = 0; i < 4; ++i)
#pragma unroll
      for (int j = 0; j < 2; ++j)
        acc[i][j] = __builtin_amdgcn_mfma_f32_16x16x32_bf16(a[i], b[j], acc[i][j], 0, 0, 0);
    __syncthreads();
  }

  // epilogue: f = wn + j*16 + l16, b = wm + i*16 + quad*4 + r
#pragma unroll
  for (int j = 0; j < 2; ++j) {
    const int f = wn + (j << 4) + l16;
    const int col = g * DUPn + f;
    const bool okf = (f < DUPn) && (col < NCLS);
    const float bv = okf ? bg[col] : 0.f;
#pragma unroll
    for (int i = 0; i < 4; ++i) {
      const int bb = wm + (i << 4) + (quad << 2);
#pragma unroll
      for (int r = 0; r < 4; ++r) {
        if (okf && bb + r < bcnt)
          out[(size_t)(b0 + bb + r) * NCLS + col] = acc[i][j][r] + bv;
      }
    }
  }
}

// ---------------------------------------------------------------------------
// Step-1 LayerNorm: out[row] = LN(2*query[row]) * g + b. fp32 in, bf16 out.
// ---------------------------------------------------------------------------
__global__ __launch_bounds__(256)
void ln_query_k(const float* __restrict__ query, const float* __restrict__ gamma,
                const float* __restrict__ beta, unsigned short* __restrict__ out)
{
  const unsigned row = blockIdx.x;
  const float* p = query + (size_t)row * Dm;
  const int tid = threadIdx.x;

  float v[3];
#pragma unroll
  for (int i = 0; i < 3; ++i) v[i] = 2.f * p[tid + (i << 8)];

  float s1 = v[0] + v[1] + v[2];
  float s2 = v[0]*v[0] + v[1]*v[1] + v[2]*v[2];
#pragma unroll
  for (int off = 32; off; off >>= 1) {
    s1 += __shfl_down(s1, off, 64);
    s2 += __shfl_down(s2, off, 64);
  }
  __shared__ float r1[4], r2[4];
  const int wave = tid >> 6, lane = tid & 63;
  if (lane == 0) { r1[wave] = s1; r2[wave] = s2; }
  __syncthreads();
  s1 = r1[0] + r1[1] + r1[2] + r1[3];
  s2 = r2[0] + r2[1] + r2[2] + r2[3];
  const float mean = s1 * (1.f / Dm);
  const float var  = s2 * (1.f / Dm) - mean * mean;
  const float inv  = rsqrtf(var + 1e-5f);
#pragma unroll
  for (int i = 0; i < 3; ++i) {
    const int c = tid + (i << 8);
    out[(size_t)row * Dm + c] = f2bf((v[i] - mean) * inv * gamma[c] + beta[c]);
  }
}

// ---------------------------------------------------------------------------
// Residual LayerNorm: out[row] = LN(in1[row] + in2[row & mask]) * g + b.
// ---------------------------------------------------------------------------
__global__ __launch_bounds__(256)
void ln_k(const unsigned short* __restrict__ in1, const unsigned short* __restrict__ in2,
          unsigned in2mask, const float* __restrict__ gamma,
          const float* __restrict__ beta, unsigned short* __restrict__ out)
{
  const unsigned row = blockIdx.x;
  const unsigned short* p1 = in1 + (size_t)row * Dm;
  const unsigned short* p2 = in2 + (size_t)(row & in2mask) * Dm;
  const int tid = threadIdx.x;

  float v[3];
#pragma unroll
  for (int i = 0; i < 3; ++i) v[i] = bf2f(p1[tid + (i << 8)]) + bf2f(p2[tid + (i << 8)]);

  float s1 = v[0] + v[1] + v[2];
  float s2 = v[0]*v[0] + v[1]*v[1] + v[2]*v[2];
#pragma unroll
  for (int off = 32; off; off >>= 1) {
    s1 += __shfl_down(s1, off, 64);
    s2 += __shfl_down(s2, off, 64);
  }
  __shared__ float r1[4], r2[4];
  const int wave = tid >> 6, lane = tid & 63;
  if (lane == 0) { r1[wave] = s1; r2[wave] = s2; }
  __syncthreads();
  s1 = r1[0] + r1[1] + r1[2] + r1[3];
  s2 = r2[0] + r2[1] + r2[2] + r2[3];
  const float mean = s1 * (1.f / Dm);
  const float var  = s2 * (1.f / Dm) - mean * mean;
  const float inv  = rsqrtf(var + 1e-5f);
#pragma unroll
  for (int i = 0; i < 3; ++i) {
    const int c = tid + (i << 8);
    out[(size_t)row * Dm + c] = f2bf((v[i] - mean) * inv * gamma[c] + beta[c]);
  }
}

// ---------------------------------------------------------------------------
// Cross-attention, one block per (head, chunk-local batch). q batch-independent.
// ---------------------------------------------------------------------------
__global__ __launch_bounds__(256)
void attn_k(const unsigned short* __restrict__ qall, const unsigned short* __restrict__ kbuf,
            const unsigned short* __restrict__ vbuf, unsigned short* __restrict__ attno,
            int b0)
{
  const int h = blockIdx.x, bl = blockIdx.y;
  const int b = b0 + bl;
  __shared__ float Ks[Ntok][HDd];
  __shared__ float Vs[Ntok][HDd];
  const int tid = threadIdx.x;
  const size_t base = (size_t)b * Ntok * Dm + h * HDd;
  for (int idx = tid; idx < Ntok * HDd; idx += 256) {
    const int n = idx / HDd, d = idx - n * HDd;
    Ks[n][d] = bf2f(kbuf[base + (size_t)n * Dm + d]);
    Vs[n][d] = bf2f(vbuf[base + (size_t)n * Dm + d]);
  }
  __syncthreads();

  const int g = tid;
  const unsigned short* qrow = qall + (size_t)g * Dm + h * HDd;
  float sc[Ntok];
#pragma unroll
  for (int n = 0; n < Ntok; ++n) sc[n] = 0.f;
  for (int kk = 0; kk < HDd; kk += 16) {
    float qv[16];
#pragma unroll
    for (int j = 0; j < 16; ++j) qv[j] = bf2f(qrow[kk + j]);
#pragma unroll 7
    for (int n = 0; n < Ntok; ++n) {
      float s = 0.f;
#pragma unroll
      for (int j = 0; j < 16; ++j) s += qv[j] * Ks[n][kk + j];
      sc[n] += s;
    }
  }
  const float scale = 0.10206207261596575f;  // 1/sqrt(96)
  float mx = -1e30f;
#pragma unroll
  for (int n = 0; n < Ntok; ++n) { sc[n] *= scale; mx = fmaxf(mx, sc[n]); }
  float sum = 0.f;
#pragma unroll
  for (int n = 0; n < Ntok; ++n) { sc[n] = __expf(sc[n] - mx); sum += sc[n]; }
  const float rs = 1.f / sum;

  unsigned short* orow = attno + ((size_t)bl * Gq + g) * Dm + h * HDd;
#pragma unroll 4
  for (int d = 0; d < HDd; ++d) {
    float s = 0.f;
#pragma unroll
    for (int n = 0; n < Ntok; ++n) s += sc[n] * Vs[n][d];
    orow[d] = f2bf(s * rs);
  }
}

// ---------------------------------------------------------------------------

static inline void gemm_launch(const unsigned short* A, const unsigned short* Bt,
                               const float* bias, unsigned short* C,
                               int M, int N, int K, int relu, hipStream_t s) {
  dim3 grid(N >> 7, M >> 7);
  gemm_bt<<<grid, 256, 0, s>>>(A, Bt, bias, C, M, N, K, relu);
}

extern "C" void kernel_launch(void* const* d_in, const int* in_sizes, int n_in,
                              void* d_out, int out_size, void* d_ws, size_t ws_size,
                              hipStream_t stream) {
  const float* x       = (const float*)d_in[0];
  const float* W_embed = (const float*)d_in[1];
  const float* b_embed = (const float*)d_in[2];
  const float* query   = (const float*)d_in[3];
  const float* Wq = (const float*)d_in[4];  const float* bq  = (const float*)d_in[5];
  const float* Wk = (const float*)d_in[6];  const float* bk  = (const float*)d_in[7];
  const float* Wv = (const float*)d_in[8];  const float* bv  = (const float*)d_in[9];
  const float* Wo = (const float*)d_in[10]; const float* bo  = (const float*)d_in[11];
  const float* g1 = (const float*)d_in[12]; const float* be1 = (const float*)d_in[13];
  const float* g2 = (const float*)d_in[14]; const float* be2 = (const float*)d_in[15];
  const float* g3 = (const float*)d_in[16]; const float* be3 = (const float*)d_in[17];
  const float* W1 = (const float*)d_in[18]; const float* b1  = (const float*)d_in[19];
  const float* W2 = (const float*)d_in[20]; const float* b2  = (const float*)d_in[21];
  const float* Wg = (const float*)d_in[22]; const float* bg  = (const float*)d_in[23];
  float* out = (float*)d_out;              // fp32 logits

  // ---- workspace carve (bf16 elements). Fixed part ~69.5 MB. ----
  unsigned short* ws    = (unsigned short*)d_ws;
  unsigned short* tbuf  = ws;                    // 256*768
  unsigned short* qall  = tbuf  + 196608;        // 256*768
  unsigned short* mem   = qall  + 196608;        // 6272*768
  unsigned short* kbuf  = mem   + 4816896;
  unsigned short* vbuf  = kbuf  + 4816896;
  unsigned short* xbf   = vbuf  + 4816896;       // 6272*2048; reused as wgT after embed GEMM
  unsigned short* wembT = xbf   + 12845056;      // 768*2048
  unsigned short* wqT   = wembT + 1572864;       // 768*768
  unsigned short* wkT   = wqT   + 589824;
  unsigned short* wvT   = wkT   + 589824;
  unsigned short* woT   = wvT   + 589824;
  unsigned short* w1T   = woT   + 589824;        // 2048*768
  unsigned short* w2T   = w1T   + 1572864;       // 768*2048
  unsigned short* attc  = w2T   + 1572864;       // chunk start
  unsigned short* wgT   = xbf;                   // 251*64*768 = 12337152 <= 12845056

  const size_t fixed_elems = 34766848;
  int CB = 128;
  while (CB > 4 && (fixed_elems + (size_t)CB * 1114112) * 2 > ws_size) CB >>= 1;
  const size_t cstride = (size_t)CB * 196608;    // CB*256*768
  unsigned short* oprc = attc + cstride;         // chunk oproj (reused as h)
  unsigned short* t2c  = oprc + cstride;         // chunk t2
  unsigned short* ff1c = t2c  + cstride;         // chunk CB*256*2048
  unsigned short* ff2c = attc;
  unsigned short* hc   = oprc;

  // 0. one-time conversions: x -> bf16; weights -> bf16 transposed [N][K]
  cvt_k<<<(Bn * Ntok * CIN / 4 + 255) / 256, 256, 0, stream>>>(x, xbf, Bn * Ntok * CIN / 4);
  transcvt_k<<<dim3(Dm / 32, CIN / 32), 256, 0, stream>>>(W_embed, wembT, CIN, Dm);
  transcvt_k<<<dim3(Dm / 32, Dm / 32),  256, 0, stream>>>(Wq, wqT, Dm, Dm);
  transcvt_k<<<dim3(Dm / 32, Dm / 32),  256, 0, stream>>>(Wk, wkT, Dm, Dm);
  transcvt_k<<<dim3(Dm / 32, Dm / 32),  256, 0, stream>>>(Wv, wvT, Dm, Dm);
  transcvt_k<<<dim3(Dm / 32, Dm / 32),  256, 0, stream>>>(Wo, woT, Dm, Dm);
  transcvt_k<<<dim3(FFd / 32, Dm / 32), 256, 0, stream>>>(W1, w1T, Dm, FFd);
  transcvt_k<<<dim3(Dm / 32, FFd / 32), 256, 0, stream>>>(W2, w2T, FFd, Dm);

  // 1. t = LN(2*query)                  [batch-independent]
  ln_query_k<<<Gq, 256, 0, stream>>>(query, g1, be1, tbuf);
  // 2. qall = t @ Wq + bq               [batch-independent]
  gemm_launch(tbuf, wqT, bq, qall, Gq, Dm, Dm, 0, stream);
  // 3. mem = relu(x @ W_embed + b_embed)   (last read of xbf)
  gemm_launch(xbf, wembT, b_embed, mem, Bn * Ntok, Dm, CIN, 1, stream);
  // 3b. Wg -> bf16 [g][64][768] into the now-dead xbf region
  wg_trans_k<<<dim3(2, Dm / 32, 251), 256, 0, stream>>>(Wg, wgT);
  // 4/5. K, V projections
  gemm_launch(mem, wkT, bk, kbuf, Bn * Ntok, Dm, Dm, 0, stream);
  gemm_launch(mem, wvT, bv, vbuf, Bn * Ntok, Dm, Dm, 0, stream);

  // ---- decoder tail, chunked over batch ----
  for (int b0 = 0; b0 < Bn; b0 += CB) {
    const int rows = CB * Gq;
    attn_k<<<dim3(Hh, CB), 256, 0, stream>>>(qall, kbuf, vbuf, attc, b0);
    gemm_launch(attc, woT, bo, oprc, rows, Dm, Dm, 0, stream);
    ln_k<<<rows, 256, 0, stream>>>(oprc, tbuf, 255u, g2, be2, t2c);
    gemm_launch(t2c, w1T, b1, ff1c, rows, FFd, Dm, 1, stream);
    gemm_launch(ff1c, w2T, b2, ff2c, rows, Dm, FFd, 0, stream);
    ln_k<<<rows, 256, 0, stream>>>(ff2c, t2c, 0xFFFFFFFFu, g3, be3, hc);
    groupfc_k<<<251, 256, 0, stream>>>(hc, wgT, bg, out, b0, CB);
  }
}

// Round 7
// 821.008 us; speedup vs baseline: 2.6063x; 1.2032x over previous
//
#include <hip/hip_runtime.h>

// Problem dims
#define Bn    128
#define Ntok  49
#define CIN   2048
#define Gq    256
#define Dm    768
#define Hh    8
#define HDd   96
#define FFd   2048
#define NCLS  12547
#define DUPn  50

typedef __attribute__((ext_vector_type(8))) short short8;
typedef __attribute__((ext_vector_type(4))) short short4v;
typedef __attribute__((ext_vector_type(4))) float floatx4;

__device__ __forceinline__ unsigned short f2bf(float f) {
  unsigned u = __builtin_bit_cast(unsigned, f);
  u += 0x7fffu + ((u >> 16) & 1u);   // round-to-nearest-even
  return (unsigned short)(u >> 16);
}
__device__ __forceinline__ float bf2f(unsigned short h) {
  return __builtin_bit_cast(float, (unsigned)h << 16);
}

// async global->LDS, 16 B per lane; LDS dest = wave-uniform base + lane*16
__device__ __forceinline__ void gl_lds16(const unsigned short* g, unsigned short* l) {
  __builtin_amdgcn_global_load_lds(
      (__attribute__((address_space(1))) void*)g,
      (__attribute__((address_space(3))) void*)l, 16, 0, 0);
}

// ---------------------------------------------------------------------------
// m97-style bf16 GEMM-BT: C[M,N] = op(A[M,K] @ Bt[N,K]^T + bias)
// ---------------------------------------------------------------------------
__global__ __launch_bounds__(256)
void gemm_bt(const unsigned short* __restrict__ A,
             const unsigned short* __restrict__ Bt,
             const float* __restrict__ bias,
             unsigned short* __restrict__ C,
             int M, int N, int K, int relu)
{
  __shared__ unsigned short As[128 * 32];
  __shared__ unsigned short Bs[128 * 32];

  const int tid  = threadIdx.x;
  const int m0   = blockIdx.y << 7;
  const int n0   = blockIdx.x << 7;
  const int wave = tid >> 6, lane = tid & 63;
  const int wm   = (wave >> 1) << 6;
  const int wn   = (wave & 1) << 6;
  const int l16  = lane & 15, quad = lane >> 4;

  const int srow = (wave << 5) + (lane >> 2);
  const int scol = (lane & 3) << 3;
  const unsigned short* gA = A  + (size_t)(m0 + srow) * K + scol;
  const unsigned short* gB = Bt + (size_t)(n0 + srow) * K + scol;
  const size_t rstep = (size_t)16 * K;
  unsigned short* lA = &As[wave << 10];
  unsigned short* lB = &Bs[wave << 10];

  floatx4 acc[4][4];
  const floatx4 zero4 = {0.f, 0.f, 0.f, 0.f};
#pragma unroll
  for (int i = 0; i < 4; ++i)
#pragma unroll
    for (int j = 0; j < 4; ++j) acc[i][j] = zero4;

  for (int k0 = 0; k0 < K; k0 += 32) {
    gl_lds16(gA + k0,         lA);
    gl_lds16(gA + k0 + rstep, lA + 512);
    gl_lds16(gB + k0,         lB);
    gl_lds16(gB + k0 + rstep, lB + 512);
    __syncthreads();

    short8 a[4], b[4];
#pragma unroll
    for (int i = 0; i < 4; ++i)
      a[i] = *(const short8*)&As[(wm + (i << 4) + l16) * 32 + (quad << 3)];
#pragma unroll
    for (int j = 0; j < 4; ++j)
      b[j] = *(const short8*)&Bs[(wn + (j << 4) + l16) * 32 + (quad << 3)];
#pragma unroll
    for (int i = 0; i < 4; ++i)
#pragma unroll
      for (int j = 0; j < 4; ++j)
        acc[i][j] = __builtin_amdgcn_mfma_f32_16x16x32_bf16(a[i], b[j], acc[i][j], 0, 0, 0);
    __syncthreads();
  }

#pragma unroll
  for (int j = 0; j < 4; ++j) {
    const int col = n0 + wn + (j << 4) + l16;
    const float bv = bias[col];
#pragma unroll
    for (int i = 0; i < 4; ++i) {
      const int rbase = m0 + wm + (i << 4) + (quad << 2);
#pragma unroll
      for (int r = 0; r < 4; ++r) {
        float v = acc[i][j][r] + bv;
        if (relu) v = fmaxf(v, 0.f);
        C[(size_t)(rbase + r) * N + col] = f2bf(v);
      }
    }
  }
}

// ---------------------------------------------------------------------------
// fp32 -> bf16 elementwise (n multiple of 4)
// ---------------------------------------------------------------------------
__global__ __launch_bounds__(256)
void cvt_k(const float* __restrict__ in, unsigned short* __restrict__ out, int n4)
{
  const int i = blockIdx.x * 256 + threadIdx.x;
  if (i < n4) {
    floatx4 v = ((const floatx4*)in)[i];
    short4v s;
    s.x = (short)f2bf(v.x); s.y = (short)f2bf(v.y);
    s.z = (short)f2bf(v.z); s.w = (short)f2bf(v.w);
    ((short4v*)out)[i] = s;
  }
}

// ---------------------------------------------------------------------------
// transpose + convert: in fp32 [K][N] -> out bf16 [N][K]. K,N % 32 == 0.
// ---------------------------------------------------------------------------
__global__ __launch_bounds__(256)
void transcvt_k(const float* __restrict__ in, unsigned short* __restrict__ out,
                int K, int N)
{
  __shared__ float tile[32][33];
  const int nb = blockIdx.x << 5, kb = blockIdx.y << 5;
  const int tx = threadIdx.x & 31, ty = threadIdx.x >> 5;   // 32 x 8
#pragma unroll
  for (int i = 0; i < 4; ++i)
    tile[ty + (i << 3)][tx] = in[(size_t)(kb + ty + (i << 3)) * N + nb + tx];
  __syncthreads();
#pragma unroll
  for (int i = 0; i < 4; ++i)
    out[(size_t)(nb + ty + (i << 3)) * K + kb + tx] = f2bf(tile[tx][ty + (i << 3)]);
}

// ---------------------------------------------------------------------------
// Wg transpose: fp32 [g][768][50] -> bf16 [g][64][768], f>=50 zero-padded.
// ---------------------------------------------------------------------------
__global__ __launch_bounds__(256)
void wg_trans_k(const float* __restrict__ Wg, unsigned short* __restrict__ out)
{
  __shared__ float tile[32][33];
  const int g  = blockIdx.z;
  const int nb = blockIdx.x << 5, kb = blockIdx.y << 5;
  const int tx = threadIdx.x & 31, ty = threadIdx.x >> 5;
  const float* in = Wg + (size_t)g * Dm * DUPn;
#pragma unroll
  for (int i = 0; i < 4; ++i) {
    const int f = nb + tx;
    tile[ty + (i << 3)][tx] =
        (f < DUPn) ? in[(size_t)(kb + ty + (i << 3)) * DUPn + f] : 0.f;
  }
  __syncthreads();
  unsigned short* o = out + (size_t)g * 64 * Dm;
#pragma unroll
  for (int i = 0; i < 4; ++i)
    o[(size_t)(nb + ty + (i << 3)) * Dm + kb + tx] = f2bf(tile[tx][ty + (i << 3)]);
}

// ---------------------------------------------------------------------------
// GroupFC via MFMA. One block per group g (251). M=128 batch, N=64, K=768.
// ---------------------------------------------------------------------------
__global__ __launch_bounds__(256)
void groupfc_k(const unsigned short* __restrict__ hb, const unsigned short* __restrict__ wgT,
               const float* __restrict__ bg, float* __restrict__ out,
               int b0, int bcnt)
{
  __shared__ unsigned short As[128 * 32];
  __shared__ unsigned short Bs[64 * 32];

  const int g    = blockIdx.x;
  const int tid  = threadIdx.x;
  const int wave = tid >> 6, lane = tid & 63;
  const int wm   = (wave & 1) << 6;
  const int wn   = (wave >> 1) << 5;
  const int l16  = lane & 15, quad = lane >> 4;

  const int srow = (wave << 5) + (lane >> 2);
  const int brow = (wave << 4) + (lane >> 2);
  const int scol = (lane & 3) << 3;
  const unsigned short* gA = hb + ((size_t)srow * Gq + g) * Dm + scol;
  const unsigned short* gB = wgT + (size_t)g * 64 * Dm + (size_t)brow * Dm + scol;
  const size_t rstepA = (size_t)16 * Gq * Dm;
  unsigned short* lA = &As[wave << 10];
  unsigned short* lB = &Bs[wave << 9];

  floatx4 acc[4][2];
  const floatx4 zero4 = {0.f, 0.f, 0.f, 0.f};
#pragma unroll
  for (int i = 0; i < 4; ++i)
#pragma unroll
    for (int j = 0; j < 2; ++j) acc[i][j] = zero4;

  for (int k0 = 0; k0 < Dm; k0 += 32) {
    gl_lds16(gA + k0,          lA);
    gl_lds16(gA + k0 + rstepA, lA + 512);
    gl_lds16(gB + k0,          lB);
    __syncthreads();

    short8 a[4], b[2];
#pragma unroll
    for (int i = 0; i < 4; ++i)
      a[i] = *(const short8*)&As[(wm + (i << 4) + l16) * 32 + (quad << 3)];
#pragma unroll
    for (int j = 0; j < 2; ++j)
      b[j] = *(const short8*)&Bs[(wn + (j << 4) + l16) * 32 + (quad << 3)];
#pragma unroll
    for (int i = 0; i < 4; ++i)
#pragma unroll
      for (int j = 0; j < 2; ++j)
        acc[i][j] = __builtin_amdgcn_mfma_f32_16x16x32_bf16(a[i], b[j], acc[i][j], 0, 0, 0);
    __syncthreads();
  }

#pragma unroll
  for (int j = 0; j < 2; ++j) {
    const int f = wn + (j << 4) + l16;
    const int col = g * DUPn + f;
    const bool okf = (f < DUPn) && (col < NCLS);
    const float bv = okf ? bg[col] : 0.f;
#pragma unroll
    for (int i = 0; i < 4; ++i) {
      const int bb = wm + (i << 4) + (quad << 2);
#pragma unroll
      for (int r = 0; r < 4; ++r) {
        if (okf && bb + r < bcnt)
          out[(size_t)(b0 + bb + r) * NCLS + col] = acc[i][j][r] + bv;
      }
    }
  }
}

// ---------------------------------------------------------------------------
// Step-1 LayerNorm: out[row] = LN(2*query[row]) * g + b. fp32 in, bf16 out.
// ---------------------------------------------------------------------------
__global__ __launch_bounds__(256)
void ln_query_k(const float* __restrict__ query, const float* __restrict__ gamma,
                const float* __restrict__ beta, unsigned short* __restrict__ out)
{
  const unsigned row = blockIdx.x;
  const float* p = query + (size_t)row * Dm;
  const int tid = threadIdx.x;

  float v[3];
#pragma unroll
  for (int i = 0; i < 3; ++i) v[i] = 2.f * p[tid + (i << 8)];

  float s1 = v[0] + v[1] + v[2];
  float s2 = v[0]*v[0] + v[1]*v[1] + v[2]*v[2];
#pragma unroll
  for (int off = 32; off; off >>= 1) {
    s1 += __shfl_down(s1, off, 64);
    s2 += __shfl_down(s2, off, 64);
  }
  __shared__ float r1[4], r2[4];
  const int wave = tid >> 6, lane = tid & 63;
  if (lane == 0) { r1[wave] = s1; r2[wave] = s2; }
  __syncthreads();
  s1 = r1[0] + r1[1] + r1[2] + r1[3];
  s2 = r2[0] + r2[1] + r2[2] + r2[3];
  const float mean = s1 * (1.f / Dm);
  const float var  = s2 * (1.f / Dm) - mean * mean;
  const float inv  = rsqrtf(var + 1e-5f);
#pragma unroll
  for (int i = 0; i < 3; ++i) {
    const int c = tid + (i << 8);
    out[(size_t)row * Dm + c] = f2bf((v[i] - mean) * inv * gamma[c] + beta[c]);
  }
}

// ---------------------------------------------------------------------------
// Residual LayerNorm: out[row] = LN(in1[row] + in2[row & mask]) * g + b.
// ---------------------------------------------------------------------------
__global__ __launch_bounds__(256)
void ln_k(const unsigned short* __restrict__ in1, const unsigned short* __restrict__ in2,
          unsigned in2mask, const float* __restrict__ gamma,
          const float* __restrict__ beta, unsigned short* __restrict__ out)
{
  const unsigned row = blockIdx.x;
  const unsigned short* p1 = in1 + (size_t)row * Dm;
  const unsigned short* p2 = in2 + (size_t)(row & in2mask) * Dm;
  const int tid = threadIdx.x;

  float v[3];
#pragma unroll
  for (int i = 0; i < 3; ++i) v[i] = bf2f(p1[tid + (i << 8)]) + bf2f(p2[tid + (i << 8)]);

  float s1 = v[0] + v[1] + v[2];
  float s2 = v[0]*v[0] + v[1]*v[1] + v[2]*v[2];
#pragma unroll
  for (int off = 32; off; off >>= 1) {
    s1 += __shfl_down(s1, off, 64);
    s2 += __shfl_down(s2, off, 64);
  }
  __shared__ float r1[4], r2[4];
  const int wave = tid >> 6, lane = tid & 63;
  if (lane == 0) { r1[wave] = s1; r2[wave] = s2; }
  __syncthreads();
  s1 = r1[0] + r1[1] + r1[2] + r1[3];
  s2 = r2[0] + r2[1] + r2[2] + r2[3];
  const float mean = s1 * (1.f / Dm);
  const float var  = s2 * (1.f / Dm) - mean * mean;
  const float inv  = rsqrtf(var + 1e-5f);
#pragma unroll
  for (int i = 0; i < 3; ++i) {
    const int c = tid + (i << 8);
    out[(size_t)row * Dm + c] = f2bf((v[i] - mean) * inv * gamma[c] + beta[c]);
  }
}

// ---------------------------------------------------------------------------
// MFMA cross-attention. One block per (head h, chunk-local batch bl).
// M=256 queries, Nk=49 keys (pad 64), d=96. S=QK^T via MFMA -> register
// softmax (shuffle over 16-lane col groups) -> P to LDS (A-layout, bf16)
// -> O=PV via MFMA. q batch-independent.
// LDS: Vt[96][64] | {Ks[64][96] then Ps[256][72]} aliased = 48 KB.
// ---------------------------------------------------------------------------
__global__ __launch_bounds__(256)
void attn_k(const unsigned short* __restrict__ qall, const unsigned short* __restrict__ kbuf,
            const unsigned short* __restrict__ vbuf, unsigned short* __restrict__ attno,
            int b0)
{
  __shared__ unsigned short smem[24576];           // 48 KB
  unsigned short* Vt = smem;                       // [96][64]
  unsigned short* Ks = smem + 6144;                // [64][96] (dead after S)
  unsigned short* Ps = smem + 6144;                // [256][72] (aliases Ks)

  const int h = blockIdx.x, bl = blockIdx.y;
  const int b = b0 + bl;
  const int tid  = threadIdx.x;
  const int wave = tid >> 6, lane = tid & 63;
  const int l16  = lane & 15, quad = lane >> 4;
  const int wm   = wave << 6;

  const size_t kvbase = (size_t)b * Ntok * Dm + h * HDd;

  // ---- stage K [64][96] (zero-pad n>=49) ----
  for (int s = tid; s < 64 * 12; s += 256) {
    const int n = s / 12, c8 = (s - n * 12) << 3;
    short8 v = {0, 0, 0, 0, 0, 0, 0, 0};
    if (n < Ntok) v = *(const short8*)(kbuf + kvbase + (size_t)n * Dm + c8);
    *(short8*)&Ks[n * 96 + c8] = v;
  }
  // ---- stage V^T [96][64]: read V rows vectorized, scatter to columns ----
  for (int s = tid; s < Ntok * 12; s += 256) {
    const int n = s / 12, c8 = (s - n * 12) << 3;
    short8 v = *(const short8*)(vbuf + kvbase + (size_t)n * Dm + c8);
#pragma unroll
    for (int j = 0; j < 8; ++j) Vt[(c8 + j) * 64 + n] = v[j];
  }
  // zero-pad Vt cols n in [49,64)
  for (int s = tid; s < 96 * 15; s += 256) {
    const int d = s / 15, n = Ntok + (s - d * 15);
    Vt[d * 64 + n] = 0;
  }
  __syncthreads();

  // ---- phase 1: S = Q @ K^T (A from global qall, B from Ks) ----
  floatx4 acc[4][4];
  const floatx4 zero4 = {0.f, 0.f, 0.f, 0.f};
#pragma unroll
  for (int i = 0; i < 4; ++i)
#pragma unroll
    for (int j = 0; j < 4; ++j) acc[i][j] = zero4;

#pragma unroll
  for (int kk = 0; kk < 96; kk += 32) {
    short8 a[4], bf[4];
#pragma unroll
    for (int i = 0; i < 4; ++i)
      a[i] = *(const short8*)(qall + (size_t)(wm + (i << 4) + l16) * Dm + h * HDd + kk + (quad << 3));
#pragma unroll
    for (int j = 0; j < 4; ++j)
      bf[j] = *(const short8*)&Ks[((j << 4) + l16) * 96 + kk + (quad << 3)];
#pragma unroll
    for (int i = 0; i < 4; ++i)
#pragma unroll
      for (int j = 0; j < 4; ++j)
        acc[i][j] = __builtin_amdgcn_mfma_f32_16x16x32_bf16(a[i], bf[j], acc[i][j], 0, 0, 0);
  }
  __syncthreads();   // all waves done reading Ks before Ps overwrites it

  // ---- phase 2: softmax over n per query row; P -> LDS (bf16, A-layout) ----
  const float scale = 0.10206207261596575f;  // 1/sqrt(96)
#pragma unroll
  for (int i = 0; i < 4; ++i) {
#pragma unroll
    for (int r = 0; r < 4; ++r) {
      float s0 = acc[i][0][r], s1 = acc[i][1][r];
      float s2 = acc[i][2][r], s3 = acc[i][3][r];
      if (l16 > 0) s3 = -1e30f;              // n = 48+l16 valid only for l16==0
      float mx = fmaxf(fmaxf(s0, s1), fmaxf(s2, s3));
      mx = fmaxf(mx, __shfl_xor(mx, 1));
      mx = fmaxf(mx, __shfl_xor(mx, 2));
      mx = fmaxf(mx, __shfl_xor(mx, 4));
      mx = fmaxf(mx, __shfl_xor(mx, 8));
      const float e0 = __expf((s0 - mx) * scale);
      const float e1 = __expf((s1 - mx) * scale);
      const float e2 = __expf((s2 - mx) * scale);
      const float e3 = __expf((s3 - mx) * scale);
      float sum = e0 + e1 + e2 + e3;
      sum += __shfl_xor(sum, 1);
      sum += __shfl_xor(sum, 2);
      sum += __shfl_xor(sum, 4);
      sum += __shfl_xor(sum, 8);
      const float rs = 1.f / sum;
      const int m = wm + (i << 4) + (quad << 2) + r;
      Ps[m * 72 +      l16] = f2bf(e0 * rs);
      Ps[m * 72 + 16 + l16] = f2bf(e1 * rs);
      Ps[m * 72 + 32 + l16] = f2bf(e2 * rs);
      Ps[m * 72 + 48 + l16] = f2bf(e3 * rs);
    }
  }
  __syncthreads();

  // ---- phase 3: O = P @ V (A = Ps, Bt = Vt) ----
  floatx4 o[4][6];
#pragma unroll
  for (int i = 0; i < 4; ++i)
#pragma unroll
    for (int j = 0; j < 6; ++j) o[i][j] = zero4;

#pragma unroll
  for (int kk = 0; kk < 64; kk += 32) {
    short8 a[4], bf[6];
#pragma unroll
    for (int i = 0; i < 4; ++i)
      a[i] = *(const short8*)&Ps[(wm + (i << 4) + l16) * 72 + kk + (quad << 3)];
#pragma unroll
    for (int j = 0; j < 6; ++j)
      bf[j] = *(const short8*)&Vt[((j << 4) + l16) * 64 + kk + (quad << 3)];
#pragma unroll
    for (int i = 0; i < 4; ++i)
#pragma unroll
      for (int j = 0; j < 6; ++j)
        o[i][j] = __builtin_amdgcn_mfma_f32_16x16x32_bf16(a[i], bf[j], o[i][j], 0, 0, 0);
  }

  // ---- phase 4: write O (col = d in lanes -> 32B contiguous per store) ----
#pragma unroll
  for (int j = 0; j < 6; ++j) {
    const int d = (j << 4) + l16;
#pragma unroll
    for (int i = 0; i < 4; ++i) {
      const int mb = wm + (i << 4) + (quad << 2);
#pragma unroll
      for (int r = 0; r < 4; ++r)
        attno[((size_t)bl * Gq + mb + r) * Dm + h * HDd + d] = f2bf(o[i][j][r]);
    }
  }
}

// ---------------------------------------------------------------------------

static inline void gemm_launch(const unsigned short* A, const unsigned short* Bt,
                               const float* bias, unsigned short* C,
                               int M, int N, int K, int relu, hipStream_t s) {
  dim3 grid(N >> 7, M >> 7);
  gemm_bt<<<grid, 256, 0, s>>>(A, Bt, bias, C, M, N, K, relu);
}

extern "C" void kernel_launch(void* const* d_in, const int* in_sizes, int n_in,
                              void* d_out, int out_size, void* d_ws, size_t ws_size,
                              hipStream_t stream) {
  const float* x       = (const float*)d_in[0];
  const float* W_embed = (const float*)d_in[1];
  const float* b_embed = (const float*)d_in[2];
  const float* query   = (const float*)d_in[3];
  const float* Wq = (const float*)d_in[4];  const float* bq  = (const float*)d_in[5];
  const float* Wk = (const float*)d_in[6];  const float* bk  = (const float*)d_in[7];
  const float* Wv = (const float*)d_in[8];  const float* bv  = (const float*)d_in[9];
  const float* Wo = (const float*)d_in[10]; const float* bo  = (const float*)d_in[11];
  const float* g1 = (const float*)d_in[12]; const float* be1 = (const float*)d_in[13];
  const float* g2 = (const float*)d_in[14]; const float* be2 = (const float*)d_in[15];
  const float* g3 = (const float*)d_in[16]; const float* be3 = (const float*)d_in[17];
  const float* W1 = (const float*)d_in[18]; const float* b1  = (const float*)d_in[19];
  const float* W2 = (const float*)d_in[20]; const float* b2  = (const float*)d_in[21];
  const float* Wg = (const float*)d_in[22]; const float* bg  = (const float*)d_in[23];
  float* out = (float*)d_out;              // fp32 logits

  // ---- workspace carve (bf16 elements). Fixed part ~69.5 MB. ----
  unsigned short* ws    = (unsigned short*)d_ws;
  unsigned short* tbuf  = ws;                    // 256*768
  unsigned short* qall  = tbuf  + 196608;        // 256*768
  unsigned short* mem   = qall  + 196608;        // 6272*768
  unsigned short* kbuf  = mem   + 4816896;
  unsigned short* vbuf  = kbuf  + 4816896;
  unsigned short* xbf   = vbuf  + 4816896;       // 6272*2048; reused as wgT
  unsigned short* wembT = xbf   + 12845056;      // 768*2048
  unsigned short* wqT   = wembT + 1572864;       // 768*768
  unsigned short* wkT   = wqT   + 589824;
  unsigned short* wvT   = wkT   + 589824;
  unsigned short* woT   = wvT   + 589824;
  unsigned short* w1T   = woT   + 589824;        // 2048*768
  unsigned short* w2T   = w1T   + 1572864;       // 768*2048
  unsigned short* attc  = w2T   + 1572864;       // chunk start
  unsigned short* wgT   = xbf;                   // 251*64*768 = 12337152

  const size_t fixed_elems = 34766848;
  int CB = 128;
  while (CB > 4 && (fixed_elems + (size_t)CB * 1114112) * 2 > ws_size) CB >>= 1;
  const size_t cstride = (size_t)CB * 196608;    // CB*256*768
  unsigned short* oprc = attc + cstride;         // chunk oproj (reused as h)
  unsigned short* t2c  = oprc + cstride;         // chunk t2
  unsigned short* ff1c = t2c  + cstride;         // chunk CB*256*2048
  unsigned short* ff2c = attc;
  unsigned short* hc   = oprc;

  // 0. one-time conversions
  cvt_k<<<(Bn * Ntok * CIN / 4 + 255) / 256, 256, 0, stream>>>(x, xbf, Bn * Ntok * CIN / 4);
  transcvt_k<<<dim3(Dm / 32, CIN / 32), 256, 0, stream>>>(W_embed, wembT, CIN, Dm);
  transcvt_k<<<dim3(Dm / 32, Dm / 32),  256, 0, stream>>>(Wq, wqT, Dm, Dm);
  transcvt_k<<<dim3(Dm / 32, Dm / 32),  256, 0, stream>>>(Wk, wkT, Dm, Dm);
  transcvt_k<<<dim3(Dm / 32, Dm / 32),  256, 0, stream>>>(Wv, wvT, Dm, Dm);
  transcvt_k<<<dim3(Dm / 32, Dm / 32),  256, 0, stream>>>(Wo, woT, Dm, Dm);
  transcvt_k<<<dim3(FFd / 32, Dm / 32), 256, 0, stream>>>(W1, w1T, Dm, FFd);
  transcvt_k<<<dim3(Dm / 32, FFd / 32), 256, 0, stream>>>(W2, w2T, FFd, Dm);

  // 1. t = LN(2*query)                  [batch-independent]
  ln_query_k<<<Gq, 256, 0, stream>>>(query, g1, be1, tbuf);
  // 2. qall = t @ Wq + bq               [batch-independent]
  gemm_launch(tbuf, wqT, bq, qall, Gq, Dm, Dm, 0, stream);
  // 3. mem = relu(x @ W_embed + b_embed)   (last read of xbf)
  gemm_launch(xbf, wembT, b_embed, mem, Bn * Ntok, Dm, CIN, 1, stream);
  // 3b. Wg -> bf16 [g][64][768] into the now-dead xbf region
  wg_trans_k<<<dim3(2, Dm / 32, 251), 256, 0, stream>>>(Wg, wgT);
  // 4/5. K, V projections
  gemm_launch(mem, wkT, bk, kbuf, Bn * Ntok, Dm, Dm, 0, stream);
  gemm_launch(mem, wvT, bv, vbuf, Bn * Ntok, Dm, Dm, 0, stream);

  // ---- decoder tail, chunked over batch ----
  for (int b0 = 0; b0 < Bn; b0 += CB) {
    const int rows = CB * Gq;
    attn_k<<<dim3(Hh, CB), 256, 0, stream>>>(qall, kbuf, vbuf, attc, b0);
    gemm_launch(attc, woT, bo, oprc, rows, Dm, Dm, 0, stream);
    ln_k<<<rows, 256, 0, stream>>>(oprc, tbuf, 255u, g2, be2, t2c);
    gemm_launch(t2c, w1T, b1, ff1c, rows, FFd, Dm, 1, stream);
    gemm_launch(ff1c, w2T, b2, ff2c, rows, Dm, FFd, 0, stream);
    ln_k<<<rows, 256, 0, stream>>>(ff2c, t2c, 0xFFFFFFFFu, g3, be3, hc);
    groupfc_k<<<251, 256, 0, stream>>>(hc, wgT, bg, out, b0, CB);
  }
}